// Round 1
// baseline (160.709 us; speedup 1.0000x reference)
//
#include <hip/hip_runtime.h>
#include <hip/hip_bf16.h>

typedef unsigned short u16;
typedef __attribute__((ext_vector_type(8))) __bf16 bf16x8;
typedef __attribute__((ext_vector_type(4))) float f32x4;
typedef __attribute__((ext_vector_type(4))) unsigned short u16x4;

#define SEQ 4096
#define DIM 1024
#define NH 16
#define HD 64
#define WIN 256

__device__ inline u16 f2bf(float f) {
  __hip_bfloat16 h = __float2bfloat16(f);
  return __builtin_bit_cast(u16, h);
}

__device__ inline void gload_lds16(const void* g, void* l) {
  auto gp = reinterpret_cast<__attribute__((address_space(1))) unsigned int*>(
      reinterpret_cast<unsigned long long>(g));
  auto lp = reinterpret_cast<__attribute__((address_space(3))) unsigned int*>(
      reinterpret_cast<unsigned long long>(l));
  __builtin_amdgcn_global_load_lds(gp, lp, 16, 0, 0);
}

__global__ __launch_bounds__(256) void cast4(const float* __restrict__ in,
                                             u16* __restrict__ out, int n) {
  int i = (blockIdx.x * 256 + threadIdx.x) * 4;
  if (i >= n) return;
  const float4 v = *reinterpret_cast<const float4*>(in + i);
  u16x4 r;
  r.x = f2bf(v.x); r.y = f2bf(v.y); r.z = f2bf(v.z); r.w = f2bf(v.w);
  *reinterpret_cast<u16x4*>(out + i) = r;
}

// C[m][n] = sum_k A[m][k]*B[n][k]  (B transposed), bias + scale, bf16 out.
// K fixed = 1024. Tile 128x128, BK=64, 4 waves each 64x64.
__global__ __launch_bounds__(256) void gemm_bt(const u16* __restrict__ A, const u16* __restrict__ B,
                                               const float* __restrict__ bias, u16* __restrict__ C,
                                               int M, int N, float scale, int bias_per_row) {
  const int K = DIM;
  __shared__ __align__(16) u16 As[128 * 64];
  __shared__ __align__(16) u16 Bs[128 * 64];
  const int bm = blockIdx.y * 128, bn = blockIdx.x * 128;
  const int tid = threadIdx.x;
  const int wid = tid >> 6, lane = tid & 63;
  const int lrow = lane & 15, lgrp = lane >> 4;
  const int wr = (wid >> 1) * 64, wc = (wid & 1) * 64;
  f32x4 zero = {0.f, 0.f, 0.f, 0.f};
  f32x4 acc[4][4];
#pragma unroll
  for (int i = 0; i < 4; ++i)
#pragma unroll
    for (int j = 0; j < 4; ++j) acc[i][j] = zero;

  for (int k0 = 0; k0 < K; k0 += 64) {
    __syncthreads();
#pragma unroll
    for (int it = 0; it < 4; ++it) {
      const int base = it * 2048 + wid * 512;  // element offset of wave segment
      const int f = base + lane * 8;
      const int r = f >> 6, c = f & 63;
      gload_lds16(A + (size_t)(bm + r) * K + k0 + c, &As[base]);
      gload_lds16(B + (size_t)(bn + r) * K + k0 + c, &Bs[base]);
    }
    __syncthreads();
#pragma unroll
    for (int ks = 0; ks < 2; ++ks) {
      bf16x8 af[4], bfr[4];
#pragma unroll
      for (int i = 0; i < 4; ++i)
        af[i] = *reinterpret_cast<const bf16x8*>(&As[(wr + i * 16 + lrow) * 64 + ks * 32 + lgrp * 8]);
#pragma unroll
      for (int j = 0; j < 4; ++j)
        bfr[j] = *reinterpret_cast<const bf16x8*>(&Bs[(wc + j * 16 + lrow) * 64 + ks * 32 + lgrp * 8]);
#pragma unroll
      for (int i = 0; i < 4; ++i)
#pragma unroll
        for (int j = 0; j < 4; ++j)
          acc[i][j] = __builtin_amdgcn_mfma_f32_16x16x32_bf16(af[i], bfr[j], acc[i][j], 0, 0, 0);
    }
  }
#pragma unroll
  for (int i = 0; i < 4; ++i)
#pragma unroll
    for (int j = 0; j < 4; ++j)
#pragma unroll
      for (int r = 0; r < 4; ++r) {
        const int row = bm + wr + i * 16 + lgrp * 4 + r;
        const int col = bn + wc + j * 16 + lrow;
        const float b = bias_per_row ? bias[row] : bias[col];
        C[(size_t)row * N + col] = f2bf((acc[i][j][r] + b) * scale);
      }
}

// Banded flash attention. Q,K: [S][D] bf16 (head h = cols h*64..h*64+63), Vt: [D][S] bf16.
// Block: (qblock of 64, head). 4 waves x 16 query rows. 32 keys per iteration.
__global__ __launch_bounds__(256) void lf_attn(const u16* __restrict__ Q, const u16* __restrict__ Kb,
                                               const u16* __restrict__ Vt, const float* __restrict__ amask,
                                               float* __restrict__ out) {
  const int h = blockIdx.y;
  const int q0 = blockIdx.x * 64;
  const int tid = threadIdx.x;
  const int wid = tid >> 6, lane = tid & 63;
  const int lrow = lane & 15, lgrp = lane >> 4;
  const int qw = q0 + wid * 16;
  __shared__ __align__(16) u16 Plds[4][16][32];

  bf16x8 qf0, qf1;
  {
    const u16* qbase = Q + (size_t)(qw + lrow) * DIM + h * HD + lgrp * 8;
    qf0 = *reinterpret_cast<const bf16x8*>(qbase);
    qf1 = *reinterpret_cast<const bf16x8*>(qbase + 32);
  }
  f32x4 zero = {0.f, 0.f, 0.f, 0.f};
  float m_r[4], l_r[4];
  f32x4 o_acc[4];
#pragma unroll
  for (int r = 0; r < 4; ++r) { m_r[r] = -1e30f; l_r[r] = 0.f; }
#pragma unroll
  for (int g = 0; g < 4; ++g) o_acc[g] = zero;

  int kstart = qw - WIN; if (kstart < 0) kstart = 0; kstart &= ~31;
  int kend = qw + 15 + WIN + 1; kend = (kend + 31) & ~31; if (kend > SEQ) kend = SEQ;

  for (int kt = kstart; kt < kend; kt += 32) {
    f32x4 s0 = zero, s1 = zero;
    {
      const u16* kb0 = Kb + (size_t)(kt + lrow) * DIM + h * HD + lgrp * 8;
      const bf16x8 k00 = *reinterpret_cast<const bf16x8*>(kb0);
      const bf16x8 k01 = *reinterpret_cast<const bf16x8*>(kb0 + 32);
      const bf16x8 k10 = *reinterpret_cast<const bf16x8*>(kb0 + 16 * DIM);
      const bf16x8 k11 = *reinterpret_cast<const bf16x8*>(kb0 + 16 * DIM + 32);
      s0 = __builtin_amdgcn_mfma_f32_16x16x32_bf16(qf0, k00, s0, 0, 0, 0);
      s0 = __builtin_amdgcn_mfma_f32_16x16x32_bf16(qf1, k01, s0, 0, 0, 0);
      s1 = __builtin_amdgcn_mfma_f32_16x16x32_bf16(qf0, k10, s1, 0, 0, 0);
      s1 = __builtin_amdgcn_mfma_f32_16x16x32_bf16(qf1, k11, s1, 0, 0, 0);
    }
    const int j0 = kt + lrow, j1 = j0 + 16;
    const float am0 = (amask[j0] != 0.f) ? -10000.f : 0.f;
    const float am1 = (amask[j1] != 0.f) ? -10000.f : 0.f;
    float p0[4], p1[4], alp[4];
#pragma unroll
    for (int r = 0; r < 4; ++r) {
      const int i_abs = qw + lgrp * 4 + r;
      const bool v0 = (j0 >= i_abs - WIN) && (j0 <= i_abs + WIN);
      const bool v1 = (j1 >= i_abs - WIN) && (j1 <= i_abs + WIN);
      const float x0 = v0 ? s0[r] + am0 : -1e30f;
      const float x1 = v1 ? s1[r] + am1 : -1e30f;
      float t = fmaxf(x0, x1);
#pragma unroll
      for (int off = 1; off < 16; off <<= 1) t = fmaxf(t, __shfl_xor(t, off, 16));
      const float mo = m_r[r];
      const float mn = fmaxf(mo, t);
      alp[r] = __expf(mo - mn);
      const float e0 = v0 ? __expf(x0 - mn) : 0.f;
      const float e1 = v1 ? __expf(x1 - mn) : 0.f;
      float rs = e0 + e1;
#pragma unroll
      for (int off = 1; off < 16; off <<= 1) rs += __shfl_xor(rs, off, 16);
      l_r[r] = l_r[r] * alp[r] + rs;
      m_r[r] = mn;
      p0[r] = e0; p1[r] = e1;
    }
#pragma unroll
    for (int g = 0; g < 4; ++g)
#pragma unroll
      for (int r = 0; r < 4; ++r) o_acc[g][r] *= alp[r];
#pragma unroll
    for (int r = 0; r < 4; ++r) {
      Plds[wid][lgrp * 4 + r][lrow] = f2bf(p0[r]);
      Plds[wid][lgrp * 4 + r][lrow + 16] = f2bf(p1[r]);
    }
    const bf16x8 pf = *reinterpret_cast<const bf16x8*>(&Plds[wid][lrow][lgrp * 8]);
    const u16* vb = Vt + (size_t)(h * HD + lrow) * SEQ + kt + lgrp * 8;
#pragma unroll
    for (int g = 0; g < 4; ++g) {
      const bf16x8 vf = *reinterpret_cast<const bf16x8*>(vb + (size_t)g * 16 * SEQ);
      o_acc[g] = __builtin_amdgcn_mfma_f32_16x16x32_bf16(pf, vf, o_acc[g], 0, 0, 0);
    }
  }
#pragma unroll
  for (int g = 0; g < 4; ++g)
#pragma unroll
    for (int r = 0; r < 4; ++r) {
      const int row = qw + lgrp * 4 + r;
      out[(size_t)row * DIM + h * HD + g * 16 + lrow] = o_acc[g][r] / l_r[r];
    }
}

extern "C" void kernel_launch(void* const* d_in, const int* in_sizes, int n_in,
                              void* d_out, int out_size, void* d_ws, size_t ws_size,
                              hipStream_t stream) {
  const float* hsrc  = (const float*)d_in[0];
  const float* amask = (const float*)d_in[1];
  const float* Wq = (const float*)d_in[3];
  const float* bq = (const float*)d_in[4];
  const float* Wk = (const float*)d_in[5];
  const float* bk = (const float*)d_in[6];
  const float* Wv = (const float*)d_in[7];
  const float* bv = (const float*)d_in[8];
  float* out = (float*)d_out;
  char* ws = (char*)d_ws;
  const size_t MB = 1024 * 1024;
  u16* Hb  = (u16*)(ws);                 // 8 MB: hidden bf16 [4096][1024]
  u16* Wqb = (u16*)(ws + 8 * MB);        // 2 MB
  u16* Wkb = (u16*)(ws + 10 * MB);       // 2 MB
  u16* Wvb = (u16*)(ws + 12 * MB);       // 2 MB
  u16* Qb  = (u16*)(ws + 14 * MB);       // 8 MB: [4096][1024] (pre-scaled)
  u16* Kbf = (u16*)(ws + 22 * MB);       // 8 MB: [4096][1024]
  u16* Vt  = (u16*)(ws + 30 * MB);       // 8 MB: [1024][4096] (transposed V)

  cast4<<<4096, 256, 0, stream>>>(hsrc, Hb, SEQ * DIM);
  cast4<<<1024, 256, 0, stream>>>(Wq, Wqb, DIM * DIM);
  cast4<<<1024, 256, 0, stream>>>(Wk, Wkb, DIM * DIM);
  cast4<<<1024, 256, 0, stream>>>(Wv, Wvb, DIM * DIM);

  dim3 gqk(DIM / 128, SEQ / 128);  // (8, 32)
  gemm_bt<<<gqk, 256, 0, stream>>>(Hb, Wqb, bq, Qb, SEQ, DIM, 0.125f, 0);
  gemm_bt<<<gqk, 256, 0, stream>>>(Hb, Wkb, bk, Kbf, SEQ, DIM, 1.0f, 0);
  dim3 gv(SEQ / 128, DIM / 128);   // (32, 8)
  gemm_bt<<<gv, 256, 0, stream>>>(Wvb, Hb, bv, Vt, DIM, SEQ, 1.0f, 1);

  dim3 ga(SEQ / 64, NH);           // (64, 16)
  lf_attn<<<ga, 256, 0, stream>>>(Qb, Kbf, Vt, amask, out);
}

// Round 2
// 140.364 us; speedup vs baseline: 1.1449x; 1.1449x over previous
//
#include <hip/hip_runtime.h>
#include <hip/hip_bf16.h>

typedef unsigned short u16;
typedef __attribute__((ext_vector_type(8))) __bf16 bf16x8;
typedef __attribute__((ext_vector_type(4))) float f32x4;
typedef __attribute__((ext_vector_type(4))) unsigned short u16x4;

#define SEQ 4096
#define DIM 1024
#define NH 16
#define HD 64
#define WIN 256

__device__ inline u16 f2bf(float f) {
  __hip_bfloat16 h = __float2bfloat16(f);
  return __builtin_bit_cast(u16, h);
}

__device__ inline void gload_lds16(const void* g, void* l) {
  auto gp = reinterpret_cast<__attribute__((address_space(1))) unsigned int*>(
      reinterpret_cast<unsigned long long>(g));
  auto lp = reinterpret_cast<__attribute__((address_space(3))) unsigned int*>(
      reinterpret_cast<unsigned long long>(l));
  __builtin_amdgcn_global_load_lds(gp, lp, 16, 0, 0);
}

__global__ __launch_bounds__(256) void cast4(const float* __restrict__ in,
                                             u16* __restrict__ out, int n) {
  int i = (blockIdx.x * 256 + threadIdx.x) * 4;
  if (i >= n) return;
  const float4 v = *reinterpret_cast<const float4*>(in + i);
  u16x4 r;
  r.x = f2bf(v.x); r.y = f2bf(v.y); r.z = f2bf(v.z); r.w = f2bf(v.w);
  *reinterpret_cast<u16x4*>(out + i) = r;
}

// Fused QKV projection: A = H [4096][1024] bf16, B = concat(Wq,Wk,Wv) [3072][1024] bf16.
// C[m][n] = sum_k A[m][k]*B[n][k] + bias[n].  Cols 0-1023 -> Qb (x0.125),
// 1024-2047 -> Kb, 2048-3071 -> Vt TRANSPOSED ([d][seq]).
// Tile 128x128, BK=64, 4 waves each 64x64.
__global__ __launch_bounds__(256) void gemm_qkv(const u16* __restrict__ A, const u16* __restrict__ B,
                                                const float* __restrict__ bias,
                                                u16* __restrict__ Qb, u16* __restrict__ Kb,
                                                u16* __restrict__ Vt) {
  const int K = DIM;
  __shared__ __align__(16) u16 As[128 * 64];
  __shared__ __align__(16) u16 Bs[128 * 64];
  const int bm = blockIdx.y * 128, bn = blockIdx.x * 128;
  const int tid = threadIdx.x;
  const int wid = tid >> 6, lane = tid & 63;
  const int lrow = lane & 15, lgrp = lane >> 4;
  const int wr = (wid >> 1) * 64, wc = (wid & 1) * 64;
  f32x4 zero = {0.f, 0.f, 0.f, 0.f};
  f32x4 acc[4][4];
#pragma unroll
  for (int i = 0; i < 4; ++i)
#pragma unroll
    for (int j = 0; j < 4; ++j) acc[i][j] = zero;

  for (int k0 = 0; k0 < K; k0 += 64) {
    __syncthreads();
#pragma unroll
    for (int it = 0; it < 4; ++it) {
      const int base = it * 2048 + wid * 512;  // element offset of wave segment
      const int f = base + lane * 8;
      const int r = f >> 6, c = f & 63;
      gload_lds16(A + (size_t)(bm + r) * K + k0 + c, &As[base]);
      gload_lds16(B + (size_t)(bn + r) * K + k0 + c, &Bs[base]);
    }
    __syncthreads();
#pragma unroll
    for (int ks = 0; ks < 2; ++ks) {
      bf16x8 af[4], bfr[4];
#pragma unroll
      for (int i = 0; i < 4; ++i)
        af[i] = *reinterpret_cast<const bf16x8*>(&As[(wr + i * 16 + lrow) * 64 + ks * 32 + lgrp * 8]);
#pragma unroll
      for (int j = 0; j < 4; ++j)
        bfr[j] = *reinterpret_cast<const bf16x8*>(&Bs[(wc + j * 16 + lrow) * 64 + ks * 32 + lgrp * 8]);
#pragma unroll
      for (int i = 0; i < 4; ++i)
#pragma unroll
        for (int j = 0; j < 4; ++j)
          acc[i][j] = __builtin_amdgcn_mfma_f32_16x16x32_bf16(af[i], bfr[j], acc[i][j], 0, 0, 0);
    }
  }
#pragma unroll
  for (int i = 0; i < 4; ++i)
#pragma unroll
    for (int j = 0; j < 4; ++j) {
      const int row0 = bm + wr + i * 16 + lgrp * 4;
      const int colg = bn + wc + j * 16 + lrow;
      const float b = bias[colg];
      if (bn < 2048) {
        u16* dst = (bn < 1024) ? Qb : Kb;
        const float sc = (bn < 1024) ? 0.125f : 1.0f;
        const int c = colg & 1023;
#pragma unroll
        for (int r = 0; r < 4; ++r)
          dst[(size_t)(row0 + r) * DIM + c] = f2bf((acc[i][j][r] + b) * sc);
      } else {
        const int dv = colg - 2048;
        u16x4 pk;
#pragma unroll
        for (int r = 0; r < 4; ++r) pk[r] = f2bf(acc[i][j][r] + b);
        *reinterpret_cast<u16x4*>(Vt + (size_t)dv * SEQ + row0) = pk;
      }
    }
}

// Banded flash attention, deferred (non-online) softmax.
// Q,K: [S][1024] bf16 (head h = cols h*64..h*64+63), Vt: [1024][S] bf16.
// Block: (qblock of 64, head). 4 waves x 16 query rows. 32 keys per iteration.
__global__ __launch_bounds__(256) void lf_attn(const u16* __restrict__ Q, const u16* __restrict__ Kb,
                                               const u16* __restrict__ Vt, const float* __restrict__ amask,
                                               float* __restrict__ out) {
  const int h = blockIdx.y;
  const int q0 = blockIdx.x * 64;
  const int tid = threadIdx.x;
  const int wid = tid >> 6, lane = tid & 63;
  const int lrow = lane & 15, lgrp = lane >> 4;
  const int qw = q0 + wid * 16;
  __shared__ __align__(16) u16 Plds[4][16][32];

  bf16x8 qf0, qf1;
  {
    const u16* qbase = Q + (size_t)(qw + lrow) * DIM + h * HD + lgrp * 8;
    qf0 = *reinterpret_cast<const bf16x8*>(qbase);
    qf1 = *reinterpret_cast<const bf16x8*>(qbase + 32);
  }
  f32x4 zero = {0.f, 0.f, 0.f, 0.f};
  f32x4 o_acc[4];
  float ps[4];
#pragma unroll
  for (int r = 0; r < 4; ++r) ps[r] = 0.f;
#pragma unroll
  for (int g = 0; g < 4; ++g) o_acc[g] = zero;

  int kstart = qw - WIN; if (kstart < 0) kstart = 0; kstart &= ~31;
  int kend = qw + 15 + WIN + 1; kend = (kend + 31) & ~31; if (kend > SEQ) kend = SEQ;

  for (int kt = kstart; kt < kend; kt += 32) {
    f32x4 s0 = zero, s1 = zero;
    {
      const u16* kb0 = Kb + (size_t)(kt + lrow) * DIM + h * HD + lgrp * 8;
      const bf16x8 k00 = *reinterpret_cast<const bf16x8*>(kb0);
      const bf16x8 k01 = *reinterpret_cast<const bf16x8*>(kb0 + 32);
      const bf16x8 k10 = *reinterpret_cast<const bf16x8*>(kb0 + 16 * DIM);
      const bf16x8 k11 = *reinterpret_cast<const bf16x8*>(kb0 + 16 * DIM + 32);
      s0 = __builtin_amdgcn_mfma_f32_16x16x32_bf16(qf0, k00, s0, 0, 0, 0);
      s0 = __builtin_amdgcn_mfma_f32_16x16x32_bf16(qf1, k01, s0, 0, 0, 0);
      s1 = __builtin_amdgcn_mfma_f32_16x16x32_bf16(qf0, k10, s1, 0, 0, 0);
      s1 = __builtin_amdgcn_mfma_f32_16x16x32_bf16(qf1, k11, s1, 0, 0, 0);
    }
    const int j0 = kt + lrow;
    const float am0 = (amask[j0] != 0.f) ? -10000.f : 0.f;
    const float am1 = (amask[j0 + 16] != 0.f) ? -10000.f : 0.f;
#pragma unroll
    for (int r = 0; r < 4; ++r) {
      const int i_abs = qw + lgrp * 4 + r;
      const int d0 = j0 - i_abs + WIN;   // valid iff 0 <= d0 <= 2*WIN
      const float e0 = ((unsigned)d0 <= 2u * WIN) ? __expf(s0[r] + am0) : 0.f;
      const float e1 = ((unsigned)(d0 + 16) <= 2u * WIN) ? __expf(s1[r] + am1) : 0.f;
      ps[r] += e0 + e1;
      Plds[wid][lgrp * 4 + r][lrow] = f2bf(e0);
      Plds[wid][lgrp * 4 + r][lrow + 16] = f2bf(e1);
    }
    const bf16x8 pf = *reinterpret_cast<const bf16x8*>(&Plds[wid][lrow][lgrp * 8]);
    const u16* vb = Vt + (size_t)(h * HD + lrow) * SEQ + kt + lgrp * 8;
#pragma unroll
    for (int g = 0; g < 4; ++g) {
      const bf16x8 vf = *reinterpret_cast<const bf16x8*>(vb + (size_t)g * 16 * SEQ);
      o_acc[g] = __builtin_amdgcn_mfma_f32_16x16x32_bf16(pf, vf, o_acc[g], 0, 0, 0);
    }
  }
#pragma unroll
  for (int r = 0; r < 4; ++r) {
#pragma unroll
    for (int off = 1; off < 16; off <<= 1) ps[r] += __shfl_xor(ps[r], off, 16);
  }
#pragma unroll
  for (int g = 0; g < 4; ++g)
#pragma unroll
    for (int r = 0; r < 4; ++r) {
      const int row = qw + lgrp * 4 + r;
      out[(size_t)row * DIM + h * HD + g * 16 + lrow] = o_acc[g][r] / ps[r];
    }
}

extern "C" void kernel_launch(void* const* d_in, const int* in_sizes, int n_in,
                              void* d_out, int out_size, void* d_ws, size_t ws_size,
                              hipStream_t stream) {
  const float* hsrc  = (const float*)d_in[0];
  const float* amask = (const float*)d_in[1];
  const float* Wq = (const float*)d_in[3];
  const float* bq = (const float*)d_in[4];
  const float* Wk = (const float*)d_in[5];
  const float* bk = (const float*)d_in[6];
  const float* Wv = (const float*)d_in[7];
  const float* bv = (const float*)d_in[8];
  float* out = (float*)d_out;
  char* ws = (char*)d_ws;
  const size_t MB = 1024 * 1024;
  u16*   Hb      = (u16*)(ws);                 // 8 MB: hidden bf16 [4096][1024]
  u16*   Wcat    = (u16*)(ws + 8 * MB);        // 6 MB: [3072][1024] bf16 (Wq|Wk|Wv)
  float* biascat = (float*)(ws + 14 * MB);     // 12 KB: [3072] f32
  u16*   Qb      = (u16*)(ws + 15 * MB);       // 8 MB: [4096][1024] (pre-scaled)
  u16*   Kbf     = (u16*)(ws + 23 * MB);       // 8 MB: [4096][1024]
  u16*   Vt      = (u16*)(ws + 31 * MB);       // 8 MB: [1024][4096] (transposed V)

  cast4<<<4096, 256, 0, stream>>>(hsrc, Hb, SEQ * DIM);
  cast4<<<1024, 256, 0, stream>>>(Wq, Wcat, DIM * DIM);
  cast4<<<1024, 256, 0, stream>>>(Wk, Wcat + DIM * DIM, DIM * DIM);
  cast4<<<1024, 256, 0, stream>>>(Wv, Wcat + 2 * DIM * DIM, DIM * DIM);
  hipMemcpyAsync(biascat,            bq, DIM * sizeof(float), hipMemcpyDeviceToDevice, stream);
  hipMemcpyAsync(biascat + DIM,      bk, DIM * sizeof(float), hipMemcpyDeviceToDevice, stream);
  hipMemcpyAsync(biascat + 2 * DIM,  bv, DIM * sizeof(float), hipMemcpyDeviceToDevice, stream);

  dim3 gq(3 * DIM / 128, SEQ / 128);  // (24, 32)
  gemm_qkv<<<gq, 256, 0, stream>>>(Hb, Wcat, biascat, Qb, Kbf, Vt);

  dim3 ga(SEQ / 64, NH);              // (64, 16)
  lf_attn<<<ga, 256, 0, stream>>>(Qb, Kbf, Vt, amask, out);
}